// Round 10
// baseline (117.887 us; speedup 1.0000x reference)
//
#include <hip/hip_runtime.h>
#include <stdint.h>

#define B_   32
#define DIM_ 16
#define H_   128
#define DM_  256
#define NH_  8
#define WP_  32     // DM/NH
#define C3_  384    // 3*NH*DIM

typedef short bf16x8 __attribute__((ext_vector_type(8)));
typedef float f32x4  __attribute__((ext_vector_type(4)));

__device__ __forceinline__ unsigned short f2bfu(float v) {
    unsigned int x = __float_as_uint(v);
    x += 0x7fffu + ((x >> 16) & 1u);   // RNE
    return (unsigned short)(x >> 16);
}
__device__ __forceinline__ unsigned cvtpk(float lo, float hi) {
    unsigned r;
    asm("v_cvt_pk_bf16_f32 %0, %1, %2" : "=v"(r) : "v"(lo), "v"(hi));
    return r;
}
// async global->LDS, 16B per lane; lds dest = wave-uniform base + lane*16
__device__ __forceinline__ void gl_lds16(const void* g, void* l) {
    __builtin_amdgcn_global_load_lds(
        (const __attribute__((address_space(1))) unsigned int*)g,
        (__attribute__((address_space(3))) unsigned int*)l, 16, 0, 0);
}
// two HW-transpose LDS reads (4 bf16 each at +32B stride), one wait
__device__ __forceinline__ void tr2(const void* p, uint2& r0, uint2& r1) {
    const __attribute__((address_space(3))) unsigned char* lp =
        (const __attribute__((address_space(3))) unsigned char*)p;
    asm volatile("s_waitcnt lgkmcnt(0)\n\t"
                 "ds_read_b64_tr_b16 %0, %2\n\t"
                 "ds_read_b64_tr_b16 %1, %2 offset:512\n\t"
                 "s_waitcnt lgkmcnt(0)"
                 : "=v"(r0), "=v"(r1) : "v"(lp) : "memory");
}

// ============================================================================
// Kernel 1 (v7): v6 structure + oc-split for TLP.
// Each block does 12 of 24 output channels (same 8h/thread, same 17 MAC/out
// tap-sharing; per-thread chain halved). 2048 blocks = 8/CU -> up to 32
// waves/CU. x rows re-read by the sibling block hit L3 (64 MB << 256 MB).
// Store path: Q/K via per-wave LDS tile + ds_read_b64_tr_b16 -> 16B coalesced
// [o][h][wp]; V direct 16B [o][wp][h]. (v6 path, known-good.)
// Grid decode: bid = (((b*16+g)*2+ht)*2+ocs), 256 thr (8 hl x 32 wp).
// ============================================================================
__global__ __launch_bounds__(256) void conv_kernel(
    const float* __restrict__ x, const float* __restrict__ w1,
    const float* __restrict__ w2, unsigned short* __restrict__ y2)
{
    __shared__ float wlds[12 * 16];                  // [ocl][0..4]=w1, [5..12]=w2
    __shared__ __align__(16) unsigned char tbuf[4][1024];  // per-wave transpose tile

    const int bid = blockIdx.x;
    const int ocs = bid & 1;
    const int ht = (bid >> 1) & 1;
    const int g  = (bid >> 2) & 15;
    const int b  = bid >> 6;
    const int oc0 = ocs * 12;
    const int tid = threadIdx.x;
    const int wp = tid & 31;
    const int hl = tid >> 5;          // 0..7
    const int h0 = ht * 64 + hl * 8;  // first output h of this thread
    const int lane = tid & 63, wv = tid >> 6;

    // ---- one-time weight staging (block-uniform); 192 entries ----
    if (tid < 192) {
        const int ocl = tid >> 4, ix = tid & 15;
        const int o = g * 24 + oc0 + ocl;
        float v = 0.f;
        if (ix < 5)       v = w1[o * 5 + ix];
        else if (ix < 13) v = w2[o * 8 + (ix - 5)];
        wlds[tid] = v;
    }

    const float* xbase = x + ((size_t)(b * DIM_ + g) * H_) * DM_ + wp * 8;

    float xr[12][8];
    #pragma unroll
    for (int r = 0; r < 12; ++r) {
        const int hr = h0 - 2 + r;
        if (hr >= 0 && hr < H_) {
            const float4* p = (const float4*)(xbase + (size_t)hr * DM_);
            float4 a = p[0], c = p[1];
            xr[r][0] = a.x; xr[r][1] = a.y; xr[r][2] = a.z; xr[r][3] = a.w;
            xr[r][4] = c.x; xr[r][5] = c.y; xr[r][6] = c.z; xr[r][7] = c.w;
        } else {
            #pragma unroll
            for (int j = 0; j < 8; ++j) xr[r][j] = 0.f;
        }
    }
    __syncthreads();

    // transpose-tile addressing (per wave; same-wave producer/consumer, no barrier)
    unsigned char* tw = &tbuf[wv][0];
    const unsigned wbo = (((lane >> 5) * 8) + 16 * (wp & 3)
                        + 256 * ((wp >> 2) & 1) + 64 * (wp >> 3)) * 2;
    const unsigned rdo = ((lane & 15) + 64 * (lane >> 4)) * 2;
    const int h_s  = ht * 64 + wv * 16 + (lane & 15);   // store h for Q/K path
    const int wp_s = (lane >> 4) * 8;                   // store wp oct base

    for (int ocl = 0; ocl < 12; ++ocl) {
        const int o = g * 24 + oc0 + ocl;
        const float* wo_ = &wlds[ocl * 16];
        float w1r[5], w2r[8];
        {
            float4 a = *(const float4*)(wo_);
            float4 c = *(const float4*)(wo_ + 4);
            float4 d = *(const float4*)(wo_ + 8);
            w1r[0] = a.x; w1r[1] = a.y; w1r[2] = a.z; w1r[3] = a.w;
            w1r[4] = c.x;
            w2r[0] = c.y; w2r[1] = c.z; w2r[2] = c.w;
            w2r[3] = d.x; w2r[4] = d.y; w2r[5] = d.z; w2r[6] = d.w;
            w2r[7] = wo_[12];
        }

        float u[12];
        #pragma unroll
        for (int r = 0; r < 12; ++r) {
            float s = w2r[0] * xr[r][0];
            #pragma unroll
            for (int j = 1; j < 8; ++j) s = fmaf(w2r[j], xr[r][j], s);
            u[r] = s;
        }

        float ys[8];
        #pragma unroll
        for (int hh = 0; hh < 8; ++hh) {
            float y = w1r[0] * u[hh];
            #pragma unroll
            for (int t = 1; t < 5; ++t) y = fmaf(w1r[t], u[hh + t], y);
            ys[hh] = y;
        }
        uint4 pk;
        pk.x = cvtpk(ys[0], ys[1]); pk.y = cvtpk(ys[2], ys[3]);
        pk.z = cvtpk(ys[4], ys[5]); pk.w = cvtpk(ys[6], ys[7]);

        if (o >= 256) {
            // V: direct 16B store, layout [o][wp][h]
            *(uint4*)(y2 + ((size_t)(b * C3_ + o) * 32 + wp) * 128 + h0) = pk;
        } else {
            // Q/K: LDS write (h-contiguous) -> 2 tr reads -> coalesced [o][h][wp]
            *(uint4*)(tw + wbo) = pk;
            uint2 r0, r1;
            tr2(tw + rdo, r0, r1);
            *(uint4*)(y2 + ((size_t)(b * C3_ + o) * 128 + h_s) * 32 + wp_s) =
                make_uint4(r0.x, r0.y, r1.x, r1.y);
        }
    }
}

// ============================================================================
// Kernel 2: MFMA attention per (b, ch). Unchanged (known-good;
// V read from [o][wp][h], Q/K from [o][h][wp]).
// ============================================================================
__global__ __launch_bounds__(256) void attn_kernel(
    const unsigned short* __restrict__ y2, unsigned short* __restrict__ z)
{
    __shared__ __align__(16) unsigned char sm[40960];

    const int tid = threadIdx.x;
    const int ch = blockIdx.x & 127, b = blockIdx.x >> 7;
    const size_t base = ((size_t)(b * C3_ + ch)) * 4096;
    const uint4* qg = (const uint4*)(y2 + base);
    const uint4* kg = (const uint4*)(y2 + base + 128 * 4096);
    const uint4* vg = (const uint4*)(y2 + base + 256 * 4096);

    #pragma unroll
    for (int r = 0; r < 2; ++r) {
        const int ci  = tid + r * 256;
        const int row = ci >> 2;
        const int c   = ci & 3;
        const int cx  = c ^ ((row >> 1) & 3);
        *(uint4*)(sm + row * 64 + cx * 16)        = qg[ci];
        *(uint4*)(sm + 8192 + row * 64 + cx * 16) = kg[ci];
        const int vd = ci >> 4;
        const int vhc = ci & 15;
        *(uint4*)(sm + 32768 + vd * 256 + ((vhc * 16) ^ ((vd & 7) << 4))) = vg[ci];
    }
    __syncthreads();

    const int l  = tid & 63, wv = tid >> 6;
    const int lm = l & 15,  lk = l >> 4;

    bf16x8 qf[2];
    #pragma unroll
    for (int t = 0; t < 2; ++t) {
        const int q = (wv * 2 + t) * 16 + lm;
        qf[t] = *(const bf16x8*)(sm + q * 64 + ((lk ^ ((q >> 1) & 3)) << 4));
    }
    f32x4 acc[8][2];
    #pragma unroll
    for (int rt = 0; rt < 8; ++rt) {
        acc[rt][0] = 0; acc[rt][1] = 0;
    }
    #pragma unroll
    for (int rt = 0; rt < 8; ++rt) {
        const int kr = rt * 16 + lm;
        bf16x8 kf = *(const bf16x8*)(sm + 8192 + kr * 64 + ((lk ^ ((kr >> 1) & 3)) << 4));
        acc[rt][0] = __builtin_amdgcn_mfma_f32_16x16x32_bf16(kf, qf[0], acc[rt][0], 0, 0, 0);
        acc[rt][1] = __builtin_amdgcn_mfma_f32_16x16x32_bf16(kf, qf[1], acc[rt][1], 0, 0, 0);
    }

    const float Cc = 0.17677669529663687f * 1.4426950408889634f;
    float inv[2];
    #pragma unroll
    for (int t = 0; t < 2; ++t) {
        float m = acc[0][t][0];
        #pragma unroll
        for (int rt = 0; rt < 8; ++rt)
            #pragma unroll
            for (int rg = 0; rg < 4; ++rg) m = fmaxf(m, acc[rt][t][rg]);
        m = fmaxf(m, __shfl_xor(m, 16));
        m = fmaxf(m, __shfl_xor(m, 32));
        float s = 0.f;
        #pragma unroll
        for (int rt = 0; rt < 8; ++rt)
            #pragma unroll
            for (int rg = 0; rg < 4; ++rg) {
                float p = exp2f((acc[rt][t][rg] - m) * Cc);
                acc[rt][t][rg] = p; s += p;
            }
        s += __shfl_xor(s, 16);
        s += __shfl_xor(s, 32);
        inv[t] = 1.0f / s;
    }

    __syncthreads();

    #pragma unroll
    for (int t = 0; t < 2; ++t) {
        const int q = (wv * 2 + t) * 16 + lm;
        #pragma unroll
        for (int rt = 0; rt < 8; ++rt) {
            unsigned u0 = cvtpk(acc[rt][t][0] * inv[t], acc[rt][t][1] * inv[t]);
            unsigned u1 = cvtpk(acc[rt][t][2] * inv[t], acc[rt][t][3] * inv[t]);
            const int kb = rt * 32 + lk * 8;
            *(uint2*)(sm + q * 256 + (kb ^ ((q & 7) << 4))) = make_uint2(u0, u1);
        }
    }
    __syncthreads();

    f32x4 o[2][2];
    o[0][0] = 0; o[0][1] = 0; o[1][0] = 0; o[1][1] = 0;
    #pragma unroll
    for (int kc = 0; kc < 4; ++kc) {
        const int cb = kc * 64 + lk * 16;
        bf16x8 av[2], bp[2];
        #pragma unroll
        for (int dt = 0; dt < 2; ++dt) {
            const int d = dt * 16 + lm;
            av[dt] = *(const bf16x8*)(sm + 32768 + d * 256 + (cb ^ ((d & 7) << 4)));
        }
        #pragma unroll
        for (int t = 0; t < 2; ++t) {
            const int q = (wv * 2 + t) * 16 + lm;
            bp[t] = *(const bf16x8*)(sm + q * 256 + (cb ^ ((q & 7) << 4)));
        }
        #pragma unroll
        for (int dt = 0; dt < 2; ++dt)
            #pragma unroll
            for (int t = 0; t < 2; ++t)
                o[dt][t] = __builtin_amdgcn_mfma_f32_16x16x32_bf16(av[dt], bp[t], o[dt][t], 0, 0, 0);
    }

    const int dd = ch >> 3, nn = ch & 7;
    unsigned short* zb = z + ((size_t)(b * DIM_ + dd)) * (H_ * DM_);
    #pragma unroll
    for (int dt = 0; dt < 2; ++dt)
        #pragma unroll
        for (int t = 0; t < 2; ++t) {
            const int q  = (wv * 2 + t) * 16 + lm;
            const int d0 = dt * 16 + lk * 4;
            unsigned u0 = cvtpk(o[dt][t][0], o[dt][t][1]);
            unsigned u1 = cvtpk(o[dt][t][2], o[dt][t][3]);
            *(uint2*)(zb + (size_t)q * DM_ + nn * 32 + d0) = make_uint2(u0, u1);
        }
}

// ============================================================================
// Kernel 3: W -> bf16 hi/lo split. Unchanged.
// ============================================================================
__global__ __launch_bounds__(256) void prep_w(
    const float* __restrict__ w, unsigned short* __restrict__ wh,
    unsigned short* __restrict__ wl)
{
    const int i = blockIdx.x * 1024 + threadIdx.x * 4;
    float4 v = *(const float4*)(w + i);
    float vv[4] = { v.x, v.y, v.z, v.w };
    unsigned short h[4], lo[4];
    #pragma unroll
    for (int j = 0; j < 4; ++j) {
        h[j] = f2bfu(vv[j]);
        float hf = __uint_as_float(((unsigned)h[j]) << 16);
        lo[j] = f2bfu(vv[j] - hf);
    }
    *(uint2*)(wh + i) = make_uint2((unsigned)h[0] | ((unsigned)h[1] << 16),
                                   (unsigned)h[2] | ((unsigned)h[3] << 16));
    *(uint2*)(wl + i) = make_uint2((unsigned)lo[0] | ((unsigned)lo[1] << 16),
                                   (unsigned)lo[2] | ((unsigned)lo[3] << 16));
}

// ============================================================================
// Kernel 4: MFMA out-projection. Unchanged (known-good).
// ============================================================================
__global__ __launch_bounds__(256) void proj_kernel(
    const unsigned short* __restrict__ zz, const unsigned short* __restrict__ wh,
    const unsigned short* __restrict__ wl, const float* __restrict__ bias,
    float* __restrict__ out)
{
    __shared__ __align__(16) unsigned char sm[65536];   // 2 bufs x 32KB
    const int tid = threadIdx.x;
    const int l = tid & 63, wv = tid >> 6, lm = l & 15, lk = l >> 4;
    const unsigned short* zs = zz + (size_t)blockIdx.x * 32768;

    const int g_off = (tid >> 2) * 256 + (tid & 3) * 8;
    const int lds_wv = wv * 1024;

    const int arow0 = wv * 32 + lm;

    f32x4 acc[2][16];
    #pragma unroll
    for (int t = 0; t < 2; ++t)
        #pragma unroll
        for (int nt = 0; nt < 16; ++nt) acc[t][nt] = 0;

    bf16x8 areg[2][2];

    #pragma unroll
    for (int i = 0; i < 8; ++i) {
        const unsigned short* g = (i < 4 ? wh : wl) + g_off + (i & 3) * 16384;
        gl_lds16(g, sm + i * 4096 + lds_wv);
    }
    #pragma unroll
    for (int t = 0; t < 2; ++t)
        areg[0][t] = *(const bf16x8*)(zs + (size_t)(arow0 + t * 16) * 256 + lk * 8);

    __syncthreads();

    #pragma unroll
    for (int kc = 0; kc < 8; ++kc) {
        const int buf = kc & 1;
        if (kc < 7) {
            #pragma unroll
            for (int i = 0; i < 8; ++i) {
                const unsigned short* g = (i < 4 ? wh : wl) + g_off + (i & 3) * 16384 + (kc + 1) * 32;
                gl_lds16(g, sm + (buf ^ 1) * 32768 + i * 4096 + lds_wv);
            }
            #pragma unroll
            for (int t = 0; t < 2; ++t)
                areg[buf ^ 1][t] = *(const bf16x8*)(zs + (size_t)(arow0 + t * 16) * 256 + (kc + 1) * 32 + lk * 8);
        }
        #pragma unroll
        for (int ph = 0; ph < 2; ++ph)
            #pragma unroll
            for (int nt = 0; nt < 16; ++nt) {
                bf16x8 bf = *(const bf16x8*)(sm + buf * 32768 + ph * 16384 + nt * 1024 + lm * 64 + lk * 16);
                acc[0][nt] = __builtin_amdgcn_mfma_f32_16x16x32_bf16(areg[buf][0], bf, acc[0][nt], 0, 0, 0);
                acc[1][nt] = __builtin_amdgcn_mfma_f32_16x16x32_bf16(areg[buf][1], bf, acc[1][nt], 0, 0, 0);
            }
        __syncthreads();
    }

    float* ob = out + (size_t)blockIdx.x * 32768;
    #pragma unroll
    for (int t = 0; t < 2; ++t)
        #pragma unroll
        for (int nt = 0; nt < 16; ++nt) {
            const float bv = bias[nt * 16 + lm];
            #pragma unroll
            for (int rg = 0; rg < 4; ++rg)
                ob[(size_t)(wv * 32 + t * 16 + lk * 4 + rg) * 256 + nt * 16 + lm] = acc[t][nt][rg] + bv;
        }
}

// ============================================================================
extern "C" void kernel_launch(void* const* d_in, const int* in_sizes, int n_in,
                              void* d_out, int out_size, void* d_ws, size_t ws_size,
                              hipStream_t stream)
{
    const float* x  = (const float*)d_in[0];
    const float* w1 = (const float*)d_in[1];
    const float* w2 = (const float*)d_in[2];
    const float* wo = (const float*)d_in[3];
    const float* wb = (const float*)d_in[4];
    float* out = (float*)d_out;

    unsigned short* y2 = (unsigned short*)d_ws;                    // 100,663,296 B
    unsigned short* zz = y2 + (size_t)B_ * C3_ * H_ * WP_;         // + 33,554,432 B
    unsigned short* wh = y2;                                       // overlays dead y2 (after attn)
    unsigned short* wl = y2 + 65536;

    conv_kernel<<<dim3(2048), dim3(256), 0, stream>>>(x, w1, w2, y2);
    attn_kernel<<<dim3(4096), dim3(256), 0, stream>>>(y2, zz);
    prep_w<<<dim3(64), dim3(256), 0, stream>>>(wo, wh, wl);
    proj_kernel<<<dim3(512), dim3(256), 0, stream>>>(zz, wh, wl, wb, out);
}

// Round 11
// 111.073 us; speedup vs baseline: 1.0614x; 1.0614x over previous
//
#include <hip/hip_runtime.h>
#include <stdint.h>

#define B_   32
#define DIM_ 16
#define H_   128
#define DM_  256
#define NH_  8
#define WP_  32     // DM/NH
#define C3_  384    // 3*NH*DIM

typedef short bf16x8 __attribute__((ext_vector_type(8)));
typedef float f32x4  __attribute__((ext_vector_type(4)));

__device__ __forceinline__ unsigned short f2bfu(float v) {
    unsigned int x = __float_as_uint(v);
    x += 0x7fffu + ((x >> 16) & 1u);   // RNE
    return (unsigned short)(x >> 16);
}
__device__ __forceinline__ unsigned cvtpk(float lo, float hi) {
    unsigned r;
    asm("v_cvt_pk_bf16_f32 %0, %1, %2" : "=v"(r) : "v"(lo), "v"(hi));
    return r;
}
// async global->LDS, 16B per lane; lds dest = wave-uniform base + lane*16
__device__ __forceinline__ void gl_lds16(const void* g, void* l) {
    __builtin_amdgcn_global_load_lds(
        (const __attribute__((address_space(1))) unsigned int*)g,
        (__attribute__((address_space(3))) unsigned int*)l, 16, 0, 0);
}
// two HW-transpose LDS reads (4 bf16 each at +32B stride), one wait
__device__ __forceinline__ void tr2(const void* p, uint2& r0, uint2& r1) {
    const __attribute__((address_space(3))) unsigned char* lp =
        (const __attribute__((address_space(3))) unsigned char*)p;
    asm volatile("s_waitcnt lgkmcnt(0)\n\t"
                 "ds_read_b64_tr_b16 %0, %2\n\t"
                 "ds_read_b64_tr_b16 %1, %2 offset:512\n\t"
                 "s_waitcnt lgkmcnt(0)"
                 : "=v"(r0), "=v"(r1) : "v"(lp) : "memory");
}

// ============================================================================
// Kernel 1 (v8): v7 work decomposition, 512-thread blocks (wave-residency
// probe). Block = (b,g,ht); threads: ocs = tid>>8 (half the channels each),
// 8h/thread, 17 MAC/out, LDS weights (all 24 ch), v6 tr-read store path.
// Grid: 32 b * 16 g * 2 ht = 1024 blocks, 512 thr (2 ocs x 8 hl x 32 wp).
// ============================================================================
__global__ __launch_bounds__(512) void conv_kernel(
    const float* __restrict__ x, const float* __restrict__ w1,
    const float* __restrict__ w2, unsigned short* __restrict__ y2)
{
    __shared__ float wlds[24 * 16];                  // [oc][0..4]=w1, [5..12]=w2
    __shared__ __align__(16) unsigned char tbuf[8][1024];  // per-wave transpose tile

    const int bid = blockIdx.x;
    const int ht = bid & 1;
    const int g  = (bid >> 1) & 15;
    const int b  = bid >> 5;
    const int tid = threadIdx.x;
    const int ocs = tid >> 8;         // 0..1 -> channel half
    const int tl  = tid & 255;
    const int wp = tl & 31;
    const int hl = tl >> 5;           // 0..7
    const int h0 = ht * 64 + hl * 8;  // first output h of this thread
    const int oc0 = ocs * 12;
    const int lane = tid & 63, wv = tid >> 6;   // wv 0..7

    // ---- one-time weight staging (block-uniform); 384 entries, 512 threads ----
    if (tid < 384) {
        const int oc = tid >> 4, ix = tid & 15;
        const int o = g * 24 + oc;
        float v = 0.f;
        if (ix < 5)       v = w1[o * 5 + ix];
        else if (ix < 13) v = w2[o * 8 + (ix - 5)];
        wlds[tid] = v;
    }

    const float* xbase = x + ((size_t)(b * DIM_ + g) * H_) * DM_ + wp * 8;

    float xr[12][8];
    #pragma unroll
    for (int r = 0; r < 12; ++r) {
        const int hr = h0 - 2 + r;
        if (hr >= 0 && hr < H_) {
            const float4* p = (const float4*)(xbase + (size_t)hr * DM_);
            float4 a = p[0], c = p[1];
            xr[r][0] = a.x; xr[r][1] = a.y; xr[r][2] = a.z; xr[r][3] = a.w;
            xr[r][4] = c.x; xr[r][5] = c.y; xr[r][6] = c.z; xr[r][7] = c.w;
        } else {
            #pragma unroll
            for (int j = 0; j < 8; ++j) xr[r][j] = 0.f;
        }
    }
    __syncthreads();

    // transpose-tile addressing (per wave; same-wave producer/consumer, no barrier)
    unsigned char* tw = &tbuf[wv][0];
    const unsigned wbo = (((lane >> 5) * 8) + 16 * (wp & 3)
                        + 256 * ((wp >> 2) & 1) + 64 * (wp >> 3)) * 2;
    const unsigned rdo = ((lane & 15) + 64 * (lane >> 4)) * 2;
    const int h_s  = ht * 64 + (wv & 3) * 16 + (lane & 15);  // store h for Q/K
    const int wp_s = (lane >> 4) * 8;                        // store wp oct base

    for (int ocl = 0; ocl < 12; ++ocl) {
        const int o = g * 24 + oc0 + ocl;
        const float* wo_ = &wlds[(oc0 + ocl) * 16];
        float w1r[5], w2r[8];
        {
            float4 a = *(const float4*)(wo_);
            float4 c = *(const float4*)(wo_ + 4);
            float4 d = *(const float4*)(wo_ + 8);
            w1r[0] = a.x; w1r[1] = a.y; w1r[2] = a.z; w1r[3] = a.w;
            w1r[4] = c.x;
            w2r[0] = c.y; w2r[1] = c.z; w2r[2] = c.w;
            w2r[3] = d.x; w2r[4] = d.y; w2r[5] = d.z; w2r[6] = d.w;
            w2r[7] = wo_[12];
        }

        float u[12];
        #pragma unroll
        for (int r = 0; r < 12; ++r) {
            float s = w2r[0] * xr[r][0];
            #pragma unroll
            for (int j = 1; j < 8; ++j) s = fmaf(w2r[j], xr[r][j], s);
            u[r] = s;
        }

        float ys[8];
        #pragma unroll
        for (int hh = 0; hh < 8; ++hh) {
            float y = w1r[0] * u[hh];
            #pragma unroll
            for (int t = 1; t < 5; ++t) y = fmaf(w1r[t], u[hh + t], y);
            ys[hh] = y;
        }
        uint4 pk;
        pk.x = cvtpk(ys[0], ys[1]); pk.y = cvtpk(ys[2], ys[3]);
        pk.z = cvtpk(ys[4], ys[5]); pk.w = cvtpk(ys[6], ys[7]);

        if (o >= 256) {
            // V: direct 16B store, layout [o][wp][h]
            *(uint4*)(y2 + ((size_t)(b * C3_ + o) * 32 + wp) * 128 + h0) = pk;
        } else {
            // Q/K: LDS write (h-contiguous) -> 2 tr reads -> coalesced [o][h][wp]
            *(uint4*)(tw + wbo) = pk;
            uint2 r0, r1;
            tr2(tw + rdo, r0, r1);
            *(uint4*)(y2 + ((size_t)(b * C3_ + o) * 128 + h_s) * 32 + wp_s) =
                make_uint4(r0.x, r0.y, r1.x, r1.y);
        }
    }
}

// ============================================================================
// Kernel 2: MFMA attention per (b, ch). Unchanged (known-good;
// V read from [o][wp][h], Q/K from [o][h][wp]).
// ============================================================================
__global__ __launch_bounds__(256) void attn_kernel(
    const unsigned short* __restrict__ y2, unsigned short* __restrict__ z)
{
    __shared__ __align__(16) unsigned char sm[40960];

    const int tid = threadIdx.x;
    const int ch = blockIdx.x & 127, b = blockIdx.x >> 7;
    const size_t base = ((size_t)(b * C3_ + ch)) * 4096;
    const uint4* qg = (const uint4*)(y2 + base);
    const uint4* kg = (const uint4*)(y2 + base + 128 * 4096);
    const uint4* vg = (const uint4*)(y2 + base + 256 * 4096);

    #pragma unroll
    for (int r = 0; r < 2; ++r) {
        const int ci  = tid + r * 256;
        const int row = ci >> 2;
        const int c   = ci & 3;
        const int cx  = c ^ ((row >> 1) & 3);
        *(uint4*)(sm + row * 64 + cx * 16)        = qg[ci];
        *(uint4*)(sm + 8192 + row * 64 + cx * 16) = kg[ci];
        const int vd = ci >> 4;
        const int vhc = ci & 15;
        *(uint4*)(sm + 32768 + vd * 256 + ((vhc * 16) ^ ((vd & 7) << 4))) = vg[ci];
    }
    __syncthreads();

    const int l  = tid & 63, wv = tid >> 6;
    const int lm = l & 15,  lk = l >> 4;

    bf16x8 qf[2];
    #pragma unroll
    for (int t = 0; t < 2; ++t) {
        const int q = (wv * 2 + t) * 16 + lm;
        qf[t] = *(const bf16x8*)(sm + q * 64 + ((lk ^ ((q >> 1) & 3)) << 4));
    }
    f32x4 acc[8][2];
    #pragma unroll
    for (int rt = 0; rt < 8; ++rt) {
        acc[rt][0] = 0; acc[rt][1] = 0;
    }
    #pragma unroll
    for (int rt = 0; rt < 8; ++rt) {
        const int kr = rt * 16 + lm;
        bf16x8 kf = *(const bf16x8*)(sm + 8192 + kr * 64 + ((lk ^ ((kr >> 1) & 3)) << 4));
        acc[rt][0] = __builtin_amdgcn_mfma_f32_16x16x32_bf16(kf, qf[0], acc[rt][0], 0, 0, 0);
        acc[rt][1] = __builtin_amdgcn_mfma_f32_16x16x32_bf16(kf, qf[1], acc[rt][1], 0, 0, 0);
    }

    const float Cc = 0.17677669529663687f * 1.4426950408889634f;
    float inv[2];
    #pragma unroll
    for (int t = 0; t < 2; ++t) {
        float m = acc[0][t][0];
        #pragma unroll
        for (int rt = 0; rt < 8; ++rt)
            #pragma unroll
            for (int rg = 0; rg < 4; ++rg) m = fmaxf(m, acc[rt][t][rg]);
        m = fmaxf(m, __shfl_xor(m, 16));
        m = fmaxf(m, __shfl_xor(m, 32));
        float s = 0.f;
        #pragma unroll
        for (int rt = 0; rt < 8; ++rt)
            #pragma unroll
            for (int rg = 0; rg < 4; ++rg) {
                float p = exp2f((acc[rt][t][rg] - m) * Cc);
                acc[rt][t][rg] = p; s += p;
            }
        s += __shfl_xor(s, 16);
        s += __shfl_xor(s, 32);
        inv[t] = 1.0f / s;
    }

    __syncthreads();

    #pragma unroll
    for (int t = 0; t < 2; ++t) {
        const int q = (wv * 2 + t) * 16 + lm;
        #pragma unroll
        for (int rt = 0; rt < 8; ++rt) {
            unsigned u0 = cvtpk(acc[rt][t][0] * inv[t], acc[rt][t][1] * inv[t]);
            unsigned u1 = cvtpk(acc[rt][t][2] * inv[t], acc[rt][t][3] * inv[t]);
            const int kb = rt * 32 + lk * 8;
            *(uint2*)(sm + q * 256 + (kb ^ ((q & 7) << 4))) = make_uint2(u0, u1);
        }
    }
    __syncthreads();

    f32x4 o[2][2];
    o[0][0] = 0; o[0][1] = 0; o[1][0] = 0; o[1][1] = 0;
    #pragma unroll
    for (int kc = 0; kc < 4; ++kc) {
        const int cb = kc * 64 + lk * 16;
        bf16x8 av[2], bp[2];
        #pragma unroll
        for (int dt = 0; dt < 2; ++dt) {
            const int d = dt * 16 + lm;
            av[dt] = *(const bf16x8*)(sm + 32768 + d * 256 + (cb ^ ((d & 7) << 4)));
        }
        #pragma unroll
        for (int t = 0; t < 2; ++t) {
            const int q = (wv * 2 + t) * 16 + lm;
            bp[t] = *(const bf16x8*)(sm + q * 256 + (cb ^ ((q & 7) << 4)));
        }
        #pragma unroll
        for (int dt = 0; dt < 2; ++dt)
            #pragma unroll
            for (int t = 0; t < 2; ++t)
                o[dt][t] = __builtin_amdgcn_mfma_f32_16x16x32_bf16(av[dt], bp[t], o[dt][t], 0, 0, 0);
    }

    const int dd = ch >> 3, nn = ch & 7;
    unsigned short* zb = z + ((size_t)(b * DIM_ + dd)) * (H_ * DM_);
    #pragma unroll
    for (int dt = 0; dt < 2; ++dt)
        #pragma unroll
        for (int t = 0; t < 2; ++t) {
            const int q  = (wv * 2 + t) * 16 + lm;
            const int d0 = dt * 16 + lk * 4;
            unsigned u0 = cvtpk(o[dt][t][0], o[dt][t][1]);
            unsigned u1 = cvtpk(o[dt][t][2], o[dt][t][3]);
            *(uint2*)(zb + (size_t)q * DM_ + nn * 32 + d0) = make_uint2(u0, u1);
        }
}

// ============================================================================
// Kernel 3: W -> bf16 hi/lo split. Unchanged.
// ============================================================================
__global__ __launch_bounds__(256) void prep_w(
    const float* __restrict__ w, unsigned short* __restrict__ wh,
    unsigned short* __restrict__ wl)
{
    const int i = blockIdx.x * 1024 + threadIdx.x * 4;
    float4 v = *(const float4*)(w + i);
    float vv[4] = { v.x, v.y, v.z, v.w };
    unsigned short h[4], lo[4];
    #pragma unroll
    for (int j = 0; j < 4; ++j) {
        h[j] = f2bfu(vv[j]);
        float hf = __uint_as_float(((unsigned)h[j]) << 16);
        lo[j] = f2bfu(vv[j] - hf);
    }
    *(uint2*)(wh + i) = make_uint2((unsigned)h[0] | ((unsigned)h[1] << 16),
                                   (unsigned)h[2] | ((unsigned)h[3] << 16));
    *(uint2*)(wl + i) = make_uint2((unsigned)lo[0] | ((unsigned)lo[1] << 16),
                                   (unsigned)lo[2] | ((unsigned)lo[3] << 16));
}

// ============================================================================
// Kernel 4 (v2): MFMA out-projection with swapped operands.
// mfma(bf=W rows, areg=z rows): D row-dim = W-row n (lk*4+rg), col-dim (lm)
// = z-row m. Per lane per (t,nt): 4 consecutive out columns at one row ->
// float4 stores, 1KB/wave-instr coalescing (was 128x4B scatter).
// Loads are byte-identical to v1 (both operands are lm-indexed row frags).
// ============================================================================
__global__ __launch_bounds__(256) void proj_kernel(
    const unsigned short* __restrict__ zz, const unsigned short* __restrict__ wh,
    const unsigned short* __restrict__ wl, const float* __restrict__ bias,
    float* __restrict__ out)
{
    __shared__ __align__(16) unsigned char sm[65536];   // 2 bufs x 32KB
    const int tid = threadIdx.x;
    const int l = tid & 63, wv = tid >> 6, lm = l & 15, lk = l >> 4;
    const unsigned short* zs = zz + (size_t)blockIdx.x * 32768;

    const int g_off = (tid >> 2) * 256 + (tid & 3) * 8;
    const int lds_wv = wv * 1024;

    const int arow0 = wv * 32 + lm;

    f32x4 acc[2][16];
    #pragma unroll
    for (int t = 0; t < 2; ++t)
        #pragma unroll
        for (int nt = 0; nt < 16; ++nt) acc[t][nt] = 0;

    bf16x8 areg[2][2];

    #pragma unroll
    for (int i = 0; i < 8; ++i) {
        const unsigned short* g = (i < 4 ? wh : wl) + g_off + (i & 3) * 16384;
        gl_lds16(g, sm + i * 4096 + lds_wv);
    }
    #pragma unroll
    for (int t = 0; t < 2; ++t)
        areg[0][t] = *(const bf16x8*)(zs + (size_t)(arow0 + t * 16) * 256 + lk * 8);

    __syncthreads();

    #pragma unroll
    for (int kc = 0; kc < 8; ++kc) {
        const int buf = kc & 1;
        if (kc < 7) {
            #pragma unroll
            for (int i = 0; i < 8; ++i) {
                const unsigned short* g = (i < 4 ? wh : wl) + g_off + (i & 3) * 16384 + (kc + 1) * 32;
                gl_lds16(g, sm + (buf ^ 1) * 32768 + i * 4096 + lds_wv);
            }
            #pragma unroll
            for (int t = 0; t < 2; ++t)
                areg[buf ^ 1][t] = *(const bf16x8*)(zs + (size_t)(arow0 + t * 16) * 256 + (kc + 1) * 32 + lk * 8);
        }
        #pragma unroll
        for (int ph = 0; ph < 2; ++ph)
            #pragma unroll
            for (int nt = 0; nt < 16; ++nt) {
                bf16x8 bf = *(const bf16x8*)(sm + buf * 32768 + ph * 16384 + nt * 1024 + lm * 64 + lk * 16);
                acc[0][nt] = __builtin_amdgcn_mfma_f32_16x16x32_bf16(bf, areg[buf][0], acc[0][nt], 0, 0, 0);
                acc[1][nt] = __builtin_amdgcn_mfma_f32_16x16x32_bf16(bf, areg[buf][1], acc[1][nt], 0, 0, 0);
            }
        __syncthreads();
    }

    // epilogue: row = wv*32 + t*16 + lm; cols nt*16 + lk*4 .. +3 (float4)
    float* ob = out + (size_t)blockIdx.x * 32768;
    #pragma unroll
    for (int t = 0; t < 2; ++t) {
        const int row = wv * 32 + t * 16 + lm;
        #pragma unroll
        for (int nt = 0; nt < 16; ++nt) {
            const int col = nt * 16 + lk * 4;
            const float4 bv = *(const float4*)(bias + col);
            float4 vv = make_float4(acc[t][nt][0] + bv.x, acc[t][nt][1] + bv.y,
                                    acc[t][nt][2] + bv.z, acc[t][nt][3] + bv.w);
            *(float4*)&ob[(size_t)row * 256 + col] = vv;
        }
    }
}

// ============================================================================
extern "C" void kernel_launch(void* const* d_in, const int* in_sizes, int n_in,
                              void* d_out, int out_size, void* d_ws, size_t ws_size,
                              hipStream_t stream)
{
    const float* x  = (const float*)d_in[0];
    const float* w1 = (const float*)d_in[1];
    const float* w2 = (const float*)d_in[2];
    const float* wo = (const float*)d_in[3];
    const float* wb = (const float*)d_in[4];
    float* out = (float*)d_out;

    unsigned short* y2 = (unsigned short*)d_ws;                    // 100,663,296 B
    unsigned short* zz = y2 + (size_t)B_ * C3_ * H_ * WP_;         // + 33,554,432 B
    unsigned short* wh = y2;                                       // overlays dead y2 (after attn)
    unsigned short* wl = y2 + 65536;

    conv_kernel<<<dim3(1024), dim3(512), 0, stream>>>(x, w1, w2, y2);
    attn_kernel<<<dim3(4096), dim3(256), 0, stream>>>(y2, zz);
    prep_w<<<dim3(64), dim3(256), 0, stream>>>(wo, wh, wl);
    proj_kernel<<<dim3(512), dim3(256), 0, stream>>>(zz, wh, wl, wb, out);
}